// Round 14
// baseline (748.224 us; speedup 1.0000x reference)
//
#include <hip/hip_runtime.h>
#include <hip/hip_bf16.h>

#define NN 50000
#define NE 800000
#define DIMX 288

typedef float float4v __attribute__((ext_vector_type(4)));
typedef short short8 __attribute__((ext_vector_type(8)));

__device__ __forceinline__ float b2f(unsigned short u) {
  return __uint_as_float(((unsigned int)u) << 16);
}
__device__ __forceinline__ float b2f_lo(unsigned int u) {
  return __uint_as_float(u << 16);
}
__device__ __forceinline__ float b2f_hi(unsigned int u) {
  return __uint_as_float(u & 0xffff0000u);
}
__device__ __forceinline__ unsigned short f2b(float f) {
  unsigned int x = __float_as_uint(f);
  x += 0x7fffu + ((x >> 16) & 1u);
  return (unsigned short)(x >> 16);
}
__device__ __forceinline__ float ldf(const void* p, long i, int f32) {
  return f32 ? ((const float*)p)[i] : b2f(((const unsigned short*)p)[i]);
}
__device__ __forceinline__ int ldidx(const int* p, long i, int i64) {
  return i64 ? p[2 * i] : p[i];
}

// ---------------- Kernel 0: weight prep + dtype detect (block 0) + zero cnt (all) ---
__global__ __launch_bounds__(256) void k_prep(
    const void* __restrict__ W0, const void* __restrict__ W1,
    const void* __restrict__ W2, const void* __restrict__ Wg,
    const void* __restrict__ Wr2,
    const unsigned short* __restrict__ pos_u16,
    const int* __restrict__ eidx_i32,
    unsigned short* __restrict__ wr2p,
    unsigned short* __restrict__ w012p,
    unsigned short* __restrict__ wgp,
    int* __restrict__ cnt,
    int* __restrict__ flags) {
  int i = blockIdx.x * 256 + threadIdx.x;
  if (i < NN) cnt[i] = 0;
  if (blockIdx.x != 0) return;
  __shared__ int lf;
  if (threadIdx.x == 0) {
    int insane = 0;
    for (int k = 0; k < 128; ++k) {
      unsigned short u = pos_u16[k];
      int e = (u >> 7) & 0xff;
      if (e >= 0xC2) insane++;          // |x| >= 2^67 impossible for bf16 pos in [0,10]
    }
    int f0 = (insane >= 2) ? 1 : 0;
    int nz = 0;
    for (int k = 1; k < 16; k += 2) nz += (eidx_i32[k] != 0);
    flags[0] = f0;
    flags[1] = (nz == 0) ? 1 : 0;       // int64 high words all zero
    lf = f0;
  }
  __syncthreads();
  const int f32 = lf;
  for (int idx = threadIdx.x; idx < 28 * 512; idx += 256) {
    int f = idx >> 9, r = idx & 511;
    int lane = r >> 3, ii = r & 7;
    int q = lane >> 4, colA = lane & 15;
    int t = f >> 1, hf = f & 1;
    int k = hf * 32 + q * 8 + ii;
    int j = t * 16 + colA;
    wr2p[idx] = f2b(ldf(Wr2, (long)k * 224 + j, f32));
  }
  for (int idx = threadIdx.x; idx < 6 * 512; idx += 256) {
    int f = idx >> 9, r = idx & 511;
    int lane = r >> 3, ii = r & 7;
    int q = lane >> 4, colA = lane & 15;
    int w = f >> 1, t = f & 1;
    const void* W = (w == 0) ? W0 : ((w == 1) ? W1 : W2);
    w012p[idx] = f2b(ldf(W, (long)(q * 8 + ii) * 32 + t * 16 + colA, f32));
  }
  for (int idx = threadIdx.x; idx < 4 * 512; idx += 256) {
    int t = idx >> 9, r = idx & 511;
    int lane = r >> 3, ii = r & 7;
    int q = lane >> 4, colA = lane & 15;
    wgp[idx] = f2b(ldf(Wg, (long)(q * 8 + ii) * 64 + t * 16 + colA, f32));
  }
}

// ---------------- Counting sort by dst: hist, 3-stage scan, scatter ----------------
__global__ __launch_bounds__(256) void k_hist(const int* __restrict__ eidx,
                                              int* __restrict__ cnt,
                                              const int* __restrict__ flags) {
  const int i64 = flags[1];
  long e = (long)blockIdx.x * 256 + threadIdx.x;
  if (e < NE) {
    int d = ldidx(eidx, NE + e, i64);
    atomicAdd(&cnt[d], 1);
  }
}

__global__ __launch_bounds__(256) void k_scan1(const int* __restrict__ cnt,
                                               int* __restrict__ bsum) {
  __shared__ int part[256];
  int t = threadIdx.x;
  int i = blockIdx.x * 256 + t;
  part[t] = (i < NN) ? cnt[i] : 0;
  __syncthreads();
  for (int off = 128; off > 0; off >>= 1) {
    if (t < off) part[t] += part[t + off];
    __syncthreads();
  }
  if (t == 0) bsum[blockIdx.x] = part[0];
}

__global__ __launch_bounds__(256) void k_scan2(const int* __restrict__ bsum,
                                               int* __restrict__ boff) {
  __shared__ int part[256];
  int t = threadIdx.x;
  int v = (t < 196) ? bsum[t] : 0;
  part[t] = v;
  __syncthreads();
  for (int off = 1; off < 256; off <<= 1) {
    int u = (t >= off) ? part[t - off] : 0;
    __syncthreads();
    part[t] += u;
    __syncthreads();
  }
  if (t < 196) boff[t] = part[t] - v;   // exclusive
}

__global__ __launch_bounds__(256) void k_scan3(const int* __restrict__ cnt,
                                               const int* __restrict__ boff,
                                               int* __restrict__ cursor) {
  __shared__ int part[256];
  int t = threadIdx.x;
  int i = blockIdx.x * 256 + t;
  int v = (i < NN) ? cnt[i] : 0;
  part[t] = v;
  __syncthreads();
  for (int off = 1; off < 256; off <<= 1) {
    int u = (t >= off) ? part[t - off] : 0;
    __syncthreads();
    part[t] += u;
    __syncthreads();
  }
  if (i < NN) cursor[i] = boff[blockIdx.x] + part[t] - v;
}

__global__ __launch_bounds__(256) void k_scatter(const int* __restrict__ eidx,
                                                 int* __restrict__ cursor,
                                                 unsigned long long* __restrict__ sedge,
                                                 const int* __restrict__ flags) {
  const int i64 = flags[1];
  long e = (long)blockIdx.x * 256 + threadIdx.x;
  if (e < NE) {
    int s = ldidx(eidx, e, i64);
    int d = ldidx(eidx, NE + e, i64);
    int p = atomicAdd(&cursor[d], 1);
    sedge[p] = ((unsigned long long)(unsigned)d << 32) | (unsigned)s;
  }
}

// ---------------- Kernel 1: si1 = irreps_linear(nodes) via MFMA -> packed bf16 ---
__global__ __launch_bounds__(256) void k_linear1(
    const void* __restrict__ nodes,
    const unsigned short* __restrict__ w012p,
    unsigned short* __restrict__ si1,
    float* __restrict__ conv,
    const int* __restrict__ flags) {
  const int f32 = flags[0];
  __shared__ __align__(16) unsigned short wf[3072];    // 6 frags x 512 shorts
  __shared__ __align__(16) unsigned int xs32[64 * 145];// 64 rows x 290 bf16
  int tid = threadIdx.x, lane = tid & 63, wid = tid >> 6;
  for (int idx = tid; idx < 384; idx += 256)
    ((uint4*)wf)[idx] = ((const uint4*)w012p)[idx];
  long nbase = (long)blockIdx.x * 64;
  for (int idx = tid; idx < 64 * 144; idx += 256) {
    int row = idx / 144, cp = idx - row * 144;
    long rowg = nbase + row; if (rowg >= NN) rowg = NN - 1;
    unsigned v;
    if (f32) {
      const float* rp = (const float*)nodes + rowg * DIMX + 2 * cp;
      v = ((unsigned)f2b(rp[1]) << 16) | f2b(rp[0]);
    } else {
      v = ((const unsigned*)nodes)[rowg * 144 + cp];
    }
    xs32[row * 145 + cp] = v;
  }
  {
    float4 z; z.x = 0.f; z.y = 0.f; z.z = 0.f; z.w = 0.f;
    long start = nbase * DIMX / 4;
    long end = start + 64 * DIMX / 4;
    long lim = (long)NN * DIMX / 4;
    if (end > lim) end = lim;
    float4* cz = (float4*)conv;
    for (long idx = start + tid; idx < end; idx += 256) cz[idx] = z;
  }
  __syncthreads();
  long tbase = nbase + (long)wid * 16;
  if (tbase >= NN) return;
  const int q = lane >> 4, colA = lane & 15;
  const unsigned short* xs16 = (const unsigned short*)xs32;
  const int rb = (wid * 16 + colA) * 290;
  short8 a0f, a1f0, a1f1, a1f2, a2f0, a2f1, a2f2, a2f3, a2f4;
  #pragma unroll
  for (int i = 0; i < 8; ++i) {
    int k = q * 8 + i;
    a0f[i]  = (short)xs16[rb + k];
    a1f0[i] = (short)xs16[rb + 32 + 3 * k + 0];
    a1f1[i] = (short)xs16[rb + 32 + 3 * k + 1];
    a1f2[i] = (short)xs16[rb + 32 + 3 * k + 2];
    a2f0[i] = (short)xs16[rb + 128 + 5 * k + 0];
    a2f1[i] = (short)xs16[rb + 128 + 5 * k + 1];
    a2f2[i] = (short)xs16[rb + 128 + 5 * k + 2];
    a2f3[i] = (short)xs16[rb + 128 + 5 * k + 3];
    a2f4[i] = (short)xs16[rb + 128 + 5 * k + 4];
  }
  const short8* wv = (const short8*)wf;
  float4v zf = {0.f, 0.f, 0.f, 0.f};
  float4v D0[2], D1[3][2], D2[5][2];
  #pragma unroll
  for (int t = 0; t < 2; ++t) {
    D0[t]    = __builtin_amdgcn_mfma_f32_16x16x32_bf16(a0f,  wv[(0 + t) * 64 + lane], zf, 0, 0, 0);
    D1[0][t] = __builtin_amdgcn_mfma_f32_16x16x32_bf16(a1f0, wv[(2 + t) * 64 + lane], zf, 0, 0, 0);
    D1[1][t] = __builtin_amdgcn_mfma_f32_16x16x32_bf16(a1f1, wv[(2 + t) * 64 + lane], zf, 0, 0, 0);
    D1[2][t] = __builtin_amdgcn_mfma_f32_16x16x32_bf16(a1f2, wv[(2 + t) * 64 + lane], zf, 0, 0, 0);
    D2[0][t] = __builtin_amdgcn_mfma_f32_16x16x32_bf16(a2f0, wv[(4 + t) * 64 + lane], zf, 0, 0, 0);
    D2[1][t] = __builtin_amdgcn_mfma_f32_16x16x32_bf16(a2f1, wv[(4 + t) * 64 + lane], zf, 0, 0, 0);
    D2[2][t] = __builtin_amdgcn_mfma_f32_16x16x32_bf16(a2f2, wv[(4 + t) * 64 + lane], zf, 0, 0, 0);
    D2[3][t] = __builtin_amdgcn_mfma_f32_16x16x32_bf16(a2f3, wv[(4 + t) * 64 + lane], zf, 0, 0, 0);
    D2[4][t] = __builtin_amdgcn_mfma_f32_16x16x32_bf16(a2f4, wv[(4 + t) * 64 + lane], zf, 0, 0, 0);
  }
  #pragma unroll
  for (int t = 0; t < 2; ++t) {
    #pragma unroll
    for (int r = 0; r < 4; ++r) {
      long node = tbase + q * 4 + r;
      if (node < NN) {
        int mj = t * 16 + colA;
        unsigned short* row = si1 + (size_t)node * DIMX;
        short8 pk;
        pk[0] = (short)f2b(D0[t][r]);
        pk[1] = (short)f2b(D1[0][t][r]);
        pk[2] = (short)f2b(D1[1][t][r]);
        pk[3] = (short)f2b(D1[2][t][r]);
        pk[4] = (short)f2b(D2[0][t][r]);
        pk[5] = (short)f2b(D2[1][t][r]);
        pk[6] = (short)f2b(D2[2][t][r]);
        pk[7] = (short)f2b(D2[3][t][r]);
        *(short8*)(row + mj * 8) = pk;
        row[256 + mj] = f2b(D2[4][t][r]);
      }
    }
  }
}

// ---- flush helper: merge halves, then plain-store (exclusive owner) or atomic ----
__device__ __forceinline__ void flushrow(float* __restrict__ conv, unsigned dstn,
                                         float accv[9], int h, int o0, int o1, int o2,
                                         bool at) {
  float tot[9];
  #pragma unroll
  for (int r = 0; r < 9; ++r) tot[r] = accv[r] + __shfl_xor(accv[r], 32, 64);
  float* cv = conv + (size_t)dstn * DIMX;
  if (at) {
    if (h == 0) {
      atomicAdd(cv + o0, tot[0]);
      atomicAdd(cv + o1, tot[1]); atomicAdd(cv + o1 + 1, tot[2]); atomicAdd(cv + o1 + 2, tot[3]);
      atomicAdd(cv + o2, tot[4]);
    } else {
      atomicAdd(cv + o2 + 1, tot[5]); atomicAdd(cv + o2 + 2, tot[6]);
      atomicAdd(cv + o2 + 3, tot[7]); atomicAdd(cv + o2 + 4, tot[8]);
    }
  } else {
    if (h == 0) {
      cv[o0] = tot[0];
      cv[o1] = tot[1]; cv[o1 + 1] = tot[2]; cv[o1 + 2] = tot[3];
      cv[o2] = tot[4];
    } else {
      cv[o2 + 1] = tot[5]; cv[o2 + 2] = tot[6];
      cv[o2 + 3] = tot[7]; cv[o2 + 4] = tot[8];
    }
  }
  #pragma unroll
  for (int r = 0; r < 9; ++r) accv[r] = 0.f;
}

// ---------------- Kernel 3: fused edge kernel (dst-sorted edges) ----------------
// R14: occupancy 2 -> 4 blocks/CU. wr2t LDS staging removed; MFMA B-fragments
// stream directly from fragment-ordered wr2p in global (L2-resident, R7-verified
// pattern, chunked 7-t). wall pitch 17 (odd => conflict-free scalar reads).
// Prefetch ring 4-deep (R12-verified). LDS ~37.9KB.
__global__ __launch_bounds__(256) void k_edges(
    const void* __restrict__ pos,
    const unsigned long long* __restrict__ sedge,
    const void* __restrict__ Wr1,
    const void* __restrict__ br1,
    const unsigned short* __restrict__ wr2p,
    const unsigned short* __restrict__ si1,
    float* __restrict__ conv,
    const int* __restrict__ flags) {
  const int f32 = flags[0];
  __shared__ __align__(16) unsigned short wall[4][3808]; // per-wave w: [j][elc], pitch 17
  __shared__ __align__(16) float wr1s[576];              // Wr1 [8][64] + br1 [64]
  __shared__ __align__(16) float geomW[4][16][8];        // per-wave Y for current group
  __shared__ __align__(16) float rbfW[4][16][8];         // per-wave rbf for current group
  __shared__ unsigned int sdvR[4][2][2][16];             // per-wave ring of 2 groups: src/dst
  int tid = threadIdx.x, lane = tid & 63, wid = tid >> 6;

  for (int idx = tid; idx < 512; idx += 256) wr1s[idx] = ldf(Wr1, idx, f32);
  if (tid < 64) wr1s[512 + tid] = ldf(br1, tid, f32);
  __syncthreads();

  size_t we = (size_t)blockIdx.x * 512 + (size_t)wid * 128;
  if (we >= (size_t)NE) return;

  const int q = lane >> 4, colA = lane & 15;
  const int h = lane >> 5, m = lane & 31;
  const int o0 = m, o1 = 32 + 3 * m, o2 = 128 + 5 * m;
  unsigned short* WL = wall[wid];
  const short8* wr2f = (const short8*)wr2p;   // [28][64] fragments

  unsigned left_dst = 0xffffffffu, right_dst = 0xffffffffu;
  if (we > 0) left_dst = (unsigned)(sedge[we - 1] >> 32);
  if (we + 128 < (size_t)NE) right_dst = (unsigned)(sedge[we + 128] >> 32);

  if (lane < 16) {
    unsigned long long pr = sedge[we + lane];
    sdvR[wid][0][0][lane] = (unsigned)(pr & 0xffffffffu);
    sdvR[wid][0][1][lane] = (unsigned)(pr >> 32);
  }
  asm volatile("" ::: "memory");

  unsigned cur_d = sdvR[wid][0][1][0];
  bool first = true;
  float accv[9];
  #pragma unroll
  for (int r = 0; r < 9; ++r) accv[r] = 0.f;

  // 4-deep prefetch ring of packed si1 row slices (dwordx4 + u16 per edge)
  uint4 A0, A1, A2, A3; unsigned short E0, E1, E2, E3;
  {
    const char* rp;
    unsigned s;
    s = sdvR[wid][0][0][0 + h]; rp = (const char*)si1 + (size_t)s * 576;
    A0 = *(const uint4*)(rp + m * 16); E0 = *(const unsigned short*)(rp + 512 + 2 * m);
    s = sdvR[wid][0][0][2 + h]; rp = (const char*)si1 + (size_t)s * 576;
    A1 = *(const uint4*)(rp + m * 16); E1 = *(const unsigned short*)(rp + 512 + 2 * m);
    s = sdvR[wid][0][0][4 + h]; rp = (const char*)si1 + (size_t)s * 576;
    A2 = *(const uint4*)(rp + m * 16); E2 = *(const unsigned short*)(rp + 512 + 2 * m);
    s = sdvR[wid][0][0][6 + h]; rp = (const char*)si1 + (size_t)s * 576;
    A3 = *(const uint4*)(rp + m * 16); E3 = *(const unsigned short*)(rp + 512 + 2 * m);
  }

  #pragma unroll 1
  for (int g = 0; g < 8; ++g) {
    // prep: sdv for group g+1, geometry+rbf for group g (lanes 0..15)
    if (lane < 16) {
      if (g < 7) {
        unsigned long long pr = sedge[we + (size_t)(g + 1) * 16 + lane];
        sdvR[wid][(g + 1) & 1][0][lane] = (unsigned)(pr & 0xffffffffu);
        sdvR[wid][(g + 1) & 1][1][lane] = (unsigned)(pr >> 32);
      }
      unsigned s = sdvR[wid][g & 1][0][lane];
      unsigned d = sdvR[wid][g & 1][1][lane];
      float rx = ldf(pos, 3 * (long)s, f32)     - ldf(pos, 3 * (long)d, f32);
      float ry = ldf(pos, 3 * (long)s + 1, f32) - ldf(pos, 3 * (long)d + 1, f32);
      float rz = ldf(pos, 3 * (long)s + 2, f32) - ldf(pos, 3 * (long)d + 2, f32);
      float dd = sqrtf(rx * rx + ry * ry + rz * rz + 1e-12f);
      float inv = 1.0f / dd;
      float ux = rx * inv, uy = ry * inv, uz = rz * inv;
      geomW[wid][lane][0] = ux; geomW[wid][lane][1] = uy; geomW[wid][lane][2] = uz;
      geomW[wid][lane][3] = ux * uy;
      geomW[wid][lane][4] = uy * uz;
      geomW[wid][lane][5] = (3.f * uz * uz - 1.f) * 0.28867513459481287f;
      geomW[wid][lane][6] = ux * uz;
      geomW[wid][lane][7] = (ux * ux - uy * uy) * 0.5f;
      #pragma unroll
      for (int k = 0; k < 8; ++k) {
        float t = dd - (float)k * (5.0f / 7.0f);
        rbfW[wid][lane][k] = __expf(-t * t);
      }
    }
    asm volatile("" ::: "memory");

    // afrag for this 16-edge group (b128 LDS reads)
    short8 afrag0, afrag1;
    {
      const float* rb = &rbfW[wid][colA][0];
      float rbv[8];
      #pragma unroll
      for (int r = 0; r < 8; ++r) rbv[r] = rb[r];
      float a0[8], a1[8];
      {
        float4v b0 = *(const float4v*)&wr1s[512 + q * 8];
        float4v b1 = *(const float4v*)&wr1s[512 + q * 8 + 4];
        float4v b2 = *(const float4v*)&wr1s[512 + 32 + q * 8];
        float4v b3 = *(const float4v*)&wr1s[512 + 32 + q * 8 + 4];
        #pragma unroll
        for (int i = 0; i < 4; ++i) {
          a0[i] = b0[i]; a0[4 + i] = b1[i];
          a1[i] = b2[i]; a1[4 + i] = b3[i];
        }
      }
      #pragma unroll
      for (int r = 0; r < 8; ++r) {
        float4v wA = *(const float4v*)&wr1s[r * 64 + q * 8];
        float4v wB = *(const float4v*)&wr1s[r * 64 + q * 8 + 4];
        float4v wC = *(const float4v*)&wr1s[r * 64 + 32 + q * 8];
        float4v wD = *(const float4v*)&wr1s[r * 64 + 32 + q * 8 + 4];
        float rv = rbv[r];
        #pragma unroll
        for (int i = 0; i < 4; ++i) {
          a0[i]     += rv * wA[i];
          a0[4 + i] += rv * wB[i];
          a1[i]     += rv * wC[i];
          a1[4 + i] += rv * wD[i];
        }
      }
      #pragma unroll
      for (int i = 0; i < 8; ++i) {
        float a = a0[i];
        afrag0[i] = (short)f2b(0.25f * a / (1.f + __expf(-a)));
        float a2 = a1[i];
        afrag1[i] = (short)f2b(0.25f * a2 / (1.f + __expf(-a2)));
      }
    }

    // 28 MFMA (B-frags streamed from global wr2p, chunked 7-t) -> unload to wall
    {
      float4v acc[14];
      #pragma unroll 1
      for (int tc = 0; tc < 2; ++tc) {
        #pragma unroll
        for (int t7 = 0; t7 < 7; ++t7) {
          int t = tc * 7 + t7;
          short8 b0 = wr2f[(t * 2 + 0) * 64 + lane];
          short8 b1 = wr2f[(t * 2 + 1) * 64 + lane];
          float4v c = {0.f, 0.f, 0.f, 0.f};
          c = __builtin_amdgcn_mfma_f32_16x16x32_bf16(afrag0, b0, c, 0, 0, 0);
          c = __builtin_amdgcn_mfma_f32_16x16x32_bf16(afrag1, b1, c, 0, 0, 0);
          acc[t] = c;
        }
      }
      #pragma unroll
      for (int t = 0; t < 14; ++t) {
        int j = t * 16 + colA;
        #pragma unroll
        for (int r = 0; r < 4; ++r)
          WL[j * 17 + q * 4 + r] = f2b(acc[t][r]);
      }
    }
    asm volatile("" ::: "memory");

    // 8 pair-iterations over the group's 16 edges
    #pragma unroll
    for (int ii = 0; ii < 8; ++ii) {
      uint4 cur; unsigned short ce;
      switch (ii & 3) {
        case 0: cur = A0; ce = E0; break;
        case 1: cur = A1; ce = E1; break;
        case 2: cur = A2; ce = E2; break;
        default: cur = A3; ce = E3; break;
      }
      // prefetch 4 iterations ahead (stays within this wave's 128-edge window)
      if (!(g == 7 && ii >= 4)) {
        int adv = 2 * ii + 8 + h;
        int pslot = (g + (adv >> 4)) & 1;
        int pidx = adv & 15;
        unsigned ps = sdvR[wid][pslot][0][pidx];
        const char* rp = (const char*)si1 + (size_t)ps * 576;
        uint4 pa = *(const uint4*)(rp + m * 16);
        unsigned short pe = *(const unsigned short*)(rp + 512 + 2 * m);
        switch (ii & 3) {
          case 0: A0 = pa; E0 = pe; break;
          case 1: A1 = pa; E1 = pe; break;
          case 2: A2 = pa; E2 = pe; break;
          default: A3 = pa; E3 = pe; break;
        }
      }

      unsigned dn0 = sdvR[wid][g & 1][1][2 * ii];
      unsigned dn1 = sdvR[wid][g & 1][1][2 * ii + 1];

      if (dn0 != cur_d) {
        bool at = first && (cur_d == left_dst);
        flushrow(conv, cur_d, accv, h, o0, o1, o2, at);
        first = false;
        cur_d = dn0;
      }

      float x0v = b2f_lo(cur.x), x1a = b2f_hi(cur.x);
      float x1b = b2f_lo(cur.y), x1c = b2f_hi(cur.y);
      float x2a = b2f_lo(cur.z), x2b = b2f_hi(cur.z);
      float x2c = b2f_lo(cur.w), x2d = b2f_hi(cur.w);
      float x2e = b2f(ce);
      const int elc = 2 * ii + h;
      float w0 = b2f(WL[(0 * 32 + m) * 17 + elc]);
      float w1 = b2f(WL[(1 * 32 + m) * 17 + elc]);
      float w2 = b2f(WL[(2 * 32 + m) * 17 + elc]);
      float w3 = b2f(WL[(3 * 32 + m) * 17 + elc]);
      float w4 = b2f(WL[(4 * 32 + m) * 17 + elc]);
      float w5 = b2f(WL[(5 * 32 + m) * 17 + elc]);
      float w6 = b2f(WL[(6 * 32 + m) * 17 + elc]);
      float4v gv0 = *(const float4v*)&geomW[wid][elc][0];
      float4v gv1 = *(const float4v*)&geomW[wid][elc][4];
      float y1x = gv0[0], y1y = gv0[1], y1z = gv0[2], y20 = gv0[3];
      float y21 = gv1[0], y22 = gv1[1], y23 = gv1[2], y24 = gv1[3];
      float d1 = x1a * y1x + x1b * y1y + x1c * y1z;
      float d2 = x2a * y20 + x2b * y21 + x2c * y22 + x2d * y23 + x2e * y24;
      float w3x0 = w3 * x0v, w5x0 = w5 * x0v;
      float v[9];
      v[0] = w0 * x0v + w4 * d1 + w6 * d2;
      v[1] = w1 * x1a + w3x0 * y1x;
      v[2] = w1 * x1b + w3x0 * y1y;
      v[3] = w1 * x1c + w3x0 * y1z;
      v[4] = w2 * x2a + w5x0 * y20;
      v[5] = w2 * x2b + w5x0 * y21;
      v[6] = w2 * x2c + w5x0 * y22;
      v[7] = w2 * x2d + w5x0 * y23;
      v[8] = w2 * x2e + w5x0 * y24;

      if (dn1 == dn0) {
        #pragma unroll
        for (int r = 0; r < 9; ++r) accv[r] += v[r];
      } else {
        if (h == 0) {
          #pragma unroll
          for (int r = 0; r < 9; ++r) accv[r] += v[r];
        }
        bool at = first && (cur_d == left_dst);
        flushrow(conv, cur_d, accv, h, o0, o1, o2, at);
        first = false;
        cur_d = dn1;
        if (h == 1) {
          #pragma unroll
          for (int r = 0; r < 9; ++r) accv[r] += v[r];
        }
      }
    }
  }
  {
    bool at = (cur_d == right_dst) || (first && (cur_d == left_dst));
    flushrow(conv, cur_d, accv, h, o0, o1, o2, at);
  }
}

// ---------------- Kernel 4: si2 = linear(conv) via MFMA; mixed; gate -> fp32 ----
__global__ __launch_bounds__(256) void k_gate(
    const float* __restrict__ conv,
    const void* __restrict__ nodes,
    const unsigned short* __restrict__ w012p,
    const unsigned short* __restrict__ wgp,
    float* __restrict__ out,
    const int* __restrict__ flags) {
  const int f32 = flags[0];
  __shared__ __align__(16) unsigned short wf[5120];     // 3072 w012 + 2048 wg
  __shared__ __align__(16) unsigned int xs32[64 * 145]; // 64 rows x 290 bf16
  __shared__ unsigned short m0b[4][16][40];             // mixed x0 (bf16)
  __shared__ float gsb[4][16][66];                      // gate values
  int tid = threadIdx.x, lane = tid & 63, wid = tid >> 6;
  for (int idx = tid; idx < 384; idx += 256)
    ((uint4*)wf)[idx] = ((const uint4*)w012p)[idx];
  for (int idx = tid; idx < 256; idx += 256)
    ((uint4*)(wf + 3072))[idx] = ((const uint4*)wgp)[idx];
  long nbase = (long)blockIdx.x * 64;
  for (int idx = tid; idx < 64 * 144; idx += 256) {
    int row = idx / 144, cp = idx - row * 144;
    long rowg = nbase + row; if (rowg >= NN) rowg = NN - 1;
    const float* rp = conv + rowg * DIMX + 2 * cp;
    xs32[row * 145 + cp] = ((unsigned)f2b(rp[1]) << 16) | f2b(rp[0]);
  }
  __syncthreads();
  long tbase = nbase + (long)wid * 16;
  if (tbase >= NN) return;
  const int q = lane >> 4, colA = lane & 15;
  const unsigned short* xs16 = (const unsigned short*)xs32;
  const int rb = (wid * 16 + colA) * 290;
  short8 a0f, a1f0, a1f1, a1f2, a2f0, a2f1, a2f2, a2f3, a2f4;
  #pragma unroll
  for (int i = 0; i < 8; ++i) {
    int k = q * 8 + i;
    a0f[i]  = (short)xs16[rb + k];
    a1f0[i] = (short)xs16[rb + 32 + 3 * k + 0];
    a1f1[i] = (short)xs16[rb + 32 + 3 * k + 1];
    a1f2[i] = (short)xs16[rb + 32 + 3 * k + 2];
    a2f0[i] = (short)xs16[rb + 128 + 5 * k + 0];
    a2f1[i] = (short)xs16[rb + 128 + 5 * k + 1];
    a2f2[i] = (short)xs16[rb + 128 + 5 * k + 2];
    a2f3[i] = (short)xs16[rb + 128 + 5 * k + 3];
    a2f4[i] = (short)xs16[rb + 128 + 5 * k + 4];
  }
  const short8* wv = (const short8*)wf;
  const short8* wg = (const short8*)(wf + 3072);
  float4v zf = {0.f, 0.f, 0.f, 0.f};
  float mixed0[2][4];
  #pragma unroll
  for (int t = 0; t < 2; ++t) {
    float4v d = __builtin_amdgcn_mfma_f32_16x16x32_bf16(a0f, wv[(0 + t) * 64 + lane], zf, 0, 0, 0);
    #pragma unroll
    for (int r = 0; r < 4; ++r) {
      long node = tbase + q * 4 + r;
      long nc = node < NN ? node : NN - 1;
      float v = d[r] + ldf(nodes, nc * DIMX + t * 16 + colA, f32);
      mixed0[t][r] = v;
      m0b[wid][q * 4 + r][t * 16 + colA] = f2b(v);
    }
  }
  asm volatile("" ::: "memory");
  short8 amf;
  #pragma unroll
  for (int i = 0; i < 8; ++i) amf[i] = (short)m0b[wid][colA][q * 8 + i];
  #pragma unroll
  for (int t = 0; t < 4; ++t) {
    float4v d = __builtin_amdgcn_mfma_f32_16x16x32_bf16(amf, wg[t * 64 + lane], zf, 0, 0, 0);
    #pragma unroll
    for (int r = 0; r < 4; ++r)
      gsb[wid][q * 4 + r][t * 16 + colA] = 1.f / (1.f + __expf(-d[r]));
  }
  asm volatile("" ::: "memory");
  float4v D1[3][2], D2[5][2];
  #pragma unroll
  for (int t = 0; t < 2; ++t) {
    D1[0][t] = __builtin_amdgcn_mfma_f32_16x16x32_bf16(a1f0, wv[(2 + t) * 64 + lane], zf, 0, 0, 0);
    D1[1][t] = __builtin_amdgcn_mfma_f32_16x16x32_bf16(a1f1, wv[(2 + t) * 64 + lane], zf, 0, 0, 0);
    D1[2][t] = __builtin_amdgcn_mfma_f32_16x16x32_bf16(a1f2, wv[(2 + t) * 64 + lane], zf, 0, 0, 0);
    D2[0][t] = __builtin_amdgcn_mfma_f32_16x16x32_bf16(a2f0, wv[(4 + t) * 64 + lane], zf, 0, 0, 0);
    D2[1][t] = __builtin_amdgcn_mfma_f32_16x16x32_bf16(a2f1, wv[(4 + t) * 64 + lane], zf, 0, 0, 0);
    D2[2][t] = __builtin_amdgcn_mfma_f32_16x16x32_bf16(a2f2, wv[(4 + t) * 64 + lane], zf, 0, 0, 0);
    D2[3][t] = __builtin_amdgcn_mfma_f32_16x16x32_bf16(a2f3, wv[(4 + t) * 64 + lane], zf, 0, 0, 0);
    D2[4][t] = __builtin_amdgcn_mfma_f32_16x16x32_bf16(a2f4, wv[(4 + t) * 64 + lane], zf, 0, 0, 0);
  }
  #pragma unroll
  for (int t = 0; t < 2; ++t) {
    #pragma unroll
    for (int r = 0; r < 4; ++r) {
      long node = tbase + q * 4 + r;
      if (node < NN) {
        int nl = q * 4 + r;
        int mj = t * 16 + colA;
        float* orow = out + (size_t)node * DIMX;
        const long nrow = node * DIMX;
        float v0 = mixed0[t][r];
        orow[mj] = v0 / (1.f + __expf(-v0));
        float g1 = gsb[wid][nl][mj];
        float g2 = gsb[wid][nl][32 + mj];
        #pragma unroll
        for (int c = 0; c < 3; ++c) {
          float v = D1[c][t][r] + ldf(nodes, nrow + 32 + 3 * mj + c, f32);
          orow[32 + 3 * mj + c] = v * g1;
        }
        #pragma unroll
        for (int c = 0; c < 5; ++c) {
          float v = D2[c][t][r] + ldf(nodes, nrow + 128 + 5 * mj + c, f32);
          orow[128 + 5 * mj + c] = v * g2;
        }
      }
    }
  }
}

extern "C" void kernel_launch(void* const* d_in, const int* in_sizes, int n_in,
                              void* d_out, int out_size, void* d_ws, size_t ws_size,
                              hipStream_t stream) {
  const void* nodes = d_in[0];
  const void* pos   = d_in[1];
  const void* W0    = d_in[2];
  const void* W1    = d_in[3];
  const void* W2    = d_in[4];
  const void* Wr1   = d_in[5];
  const void* br1   = d_in[6];
  const void* Wr2   = d_in[7];
  const void* Wg    = d_in[8];
  const int* eidx   = (const int*)d_in[10];

  // workspace layout
  int* flags = (int*)d_ws;
  unsigned short* si1 = (unsigned short*)((char*)d_ws + 256);
  size_t conv_off = 256 + (size_t)NN * DIMX * 2;                 // 28,800,256
  float* conv = (float*)((char*)d_ws + conv_off);
  size_t cnt_off = conv_off + (size_t)NN * DIMX * 4;             // 86,400,256
  int* cnt    = (int*)((char*)d_ws + cnt_off);
  int* cursor = (int*)((char*)d_ws + cnt_off + (size_t)NN * 4);  // 86,600,256
  unsigned long long* sedge =
      (unsigned long long*)((char*)d_ws + cnt_off + 2 * (size_t)NN * 4);  // 86,800,256
  unsigned short* wr2p =
      (unsigned short*)((char*)d_ws + cnt_off + 2 * (size_t)NN * 4 + (size_t)NE * 8); // 93,200,256
  unsigned short* w012p = wr2p + 28 * 512;                        // +28,672 B
  unsigned short* wgp   = w012p + 6 * 512;                        // +6,144 B
  int* bsum = (int*)(wgp + 4 * 512);                              // +4,096 B
  int* boff = bsum + 256;
  float* out = (float*)d_out;

  hipLaunchKernelGGL(k_prep, dim3((NN + 255) / 256), dim3(256), 0, stream,
                     W0, W1, W2, Wg, Wr2,
                     (const unsigned short*)pos, eidx,
                     wr2p, w012p, wgp, cnt, flags);
  // counting sort of edges by dst (hist + 3-stage parallel scan + scatter)
  hipLaunchKernelGGL(k_hist, dim3((NE + 255) / 256), dim3(256), 0, stream, eidx, cnt, flags);
  hipLaunchKernelGGL(k_scan1, dim3((NN + 255) / 256), dim3(256), 0, stream, cnt, bsum);
  hipLaunchKernelGGL(k_scan2, dim3(1), dim3(256), 0, stream, bsum, boff);
  hipLaunchKernelGGL(k_scan3, dim3((NN + 255) / 256), dim3(256), 0, stream, cnt, boff, cursor);
  hipLaunchKernelGGL(k_scatter, dim3((NE + 255) / 256), dim3(256), 0, stream,
                     eidx, cursor, sedge, flags);
  // node pipeline (MFMA + coalesced LDS staging; k_linear1 also zeroes conv)
  hipLaunchKernelGGL(k_linear1, dim3((NN + 63) / 64), dim3(256), 0, stream,
                     nodes, w012p, si1, conv, flags);
  hipLaunchKernelGGL(k_edges, dim3((NE + 511) / 512), dim3(256), 0, stream,
                     pos, sedge, Wr1, br1, wr2p, si1, conv, flags);
  hipLaunchKernelGGL(k_gate, dim3((NN + 63) / 64), dim3(256), 0, stream,
                     conv, nodes, w012p, wgp, out, flags);
}

// Round 15
// 520.219 us; speedup vs baseline: 1.4383x; 1.4383x over previous
//
#include <hip/hip_runtime.h>
#include <hip/hip_bf16.h>

#define NN 50000
#define NE 800000
#define DIMX 288

typedef float float4v __attribute__((ext_vector_type(4)));
typedef short short8 __attribute__((ext_vector_type(8)));

__device__ __forceinline__ float b2f(unsigned short u) {
  return __uint_as_float(((unsigned int)u) << 16);
}
__device__ __forceinline__ float b2f_lo(unsigned int u) {
  return __uint_as_float(u << 16);
}
__device__ __forceinline__ float b2f_hi(unsigned int u) {
  return __uint_as_float(u & 0xffff0000u);
}
__device__ __forceinline__ unsigned short f2b(float f) {
  unsigned int x = __float_as_uint(f);
  x += 0x7fffu + ((x >> 16) & 1u);
  return (unsigned short)(x >> 16);
}
__device__ __forceinline__ float ldf(const void* p, long i, int f32) {
  return f32 ? ((const float*)p)[i] : b2f(((const unsigned short*)p)[i]);
}
__device__ __forceinline__ int ldidx(const int* p, long i, int i64) {
  return i64 ? p[2 * i] : p[i];
}

// ---------------- Kernel 0: weight prep + dtype detect (block 0) + zero cnt (all) ---
__global__ __launch_bounds__(256) void k_prep(
    const void* __restrict__ W0, const void* __restrict__ W1,
    const void* __restrict__ W2, const void* __restrict__ Wg,
    const void* __restrict__ Wr2,
    const unsigned short* __restrict__ pos_u16,
    const int* __restrict__ eidx_i32,
    unsigned short* __restrict__ wr2p,
    unsigned short* __restrict__ w012p,
    unsigned short* __restrict__ wgp,
    int* __restrict__ cnt,
    int* __restrict__ flags) {
  int i = blockIdx.x * 256 + threadIdx.x;
  if (i < NN) cnt[i] = 0;
  if (blockIdx.x != 0) return;
  __shared__ int lf;
  if (threadIdx.x == 0) {
    int insane = 0;
    for (int k = 0; k < 128; ++k) {
      unsigned short u = pos_u16[k];
      int e = (u >> 7) & 0xff;
      if (e >= 0xC2) insane++;          // |x| >= 2^67 impossible for bf16 pos in [0,10]
    }
    int f0 = (insane >= 2) ? 1 : 0;
    int nz = 0;
    for (int k = 1; k < 16; k += 2) nz += (eidx_i32[k] != 0);
    flags[0] = f0;
    flags[1] = (nz == 0) ? 1 : 0;       // int64 high words all zero
    lf = f0;
  }
  __syncthreads();
  const int f32 = lf;
  for (int idx = threadIdx.x; idx < 28 * 512; idx += 256) {
    int f = idx >> 9, r = idx & 511;
    int lane = r >> 3, ii = r & 7;
    int q = lane >> 4, colA = lane & 15;
    int t = f >> 1, hf = f & 1;
    int k = hf * 32 + q * 8 + ii;
    int j = t * 16 + colA;
    wr2p[idx] = f2b(ldf(Wr2, (long)k * 224 + j, f32));
  }
  for (int idx = threadIdx.x; idx < 6 * 512; idx += 256) {
    int f = idx >> 9, r = idx & 511;
    int lane = r >> 3, ii = r & 7;
    int q = lane >> 4, colA = lane & 15;
    int w = f >> 1, t = f & 1;
    const void* W = (w == 0) ? W0 : ((w == 1) ? W1 : W2);
    w012p[idx] = f2b(ldf(W, (long)(q * 8 + ii) * 32 + t * 16 + colA, f32));
  }
  for (int idx = threadIdx.x; idx < 4 * 512; idx += 256) {
    int t = idx >> 9, r = idx & 511;
    int lane = r >> 3, ii = r & 7;
    int q = lane >> 4, colA = lane & 15;
    wgp[idx] = f2b(ldf(Wg, (long)(q * 8 + ii) * 64 + t * 16 + colA, f32));
  }
}

// ---------------- Counting sort by dst: hist(+rank), 3-stage scan, scatter ----------
__global__ __launch_bounds__(256) void k_hist(const int* __restrict__ eidx,
                                              int* __restrict__ cnt,
                                              int* __restrict__ rank_,
                                              const int* __restrict__ flags) {
  const int i64 = flags[1];
  long e = (long)blockIdx.x * 256 + threadIdx.x;
  if (e < NE) {
    int d = ldidx(eidx, NE + e, i64);
    rank_[e] = atomicAdd(&cnt[d], 1);
  }
}

__global__ __launch_bounds__(256) void k_scan1(const int* __restrict__ cnt,
                                               int* __restrict__ bsum) {
  __shared__ int part[256];
  int t = threadIdx.x;
  int i = blockIdx.x * 256 + t;
  part[t] = (i < NN) ? cnt[i] : 0;
  __syncthreads();
  for (int off = 128; off > 0; off >>= 1) {
    if (t < off) part[t] += part[t + off];
    __syncthreads();
  }
  if (t == 0) bsum[blockIdx.x] = part[0];
}

__global__ __launch_bounds__(256) void k_scan2(const int* __restrict__ bsum,
                                               int* __restrict__ boff) {
  __shared__ int part[256];
  int t = threadIdx.x;
  int v = (t < 196) ? bsum[t] : 0;
  part[t] = v;
  __syncthreads();
  for (int off = 1; off < 256; off <<= 1) {
    int u = (t >= off) ? part[t - off] : 0;
    __syncthreads();
    part[t] += u;
    __syncthreads();
  }
  if (t < 196) boff[t] = part[t] - v;   // exclusive
}

__global__ __launch_bounds__(256) void k_scan3(const int* __restrict__ cnt,
                                               const int* __restrict__ boff,
                                               int* __restrict__ cursor) {
  __shared__ int part[256];
  int t = threadIdx.x;
  int i = blockIdx.x * 256 + t;
  int v = (i < NN) ? cnt[i] : 0;
  part[t] = v;
  __syncthreads();
  for (int off = 1; off < 256; off <<= 1) {
    int u = (t >= off) ? part[t - off] : 0;
    __syncthreads();
    part[t] += u;
    __syncthreads();
  }
  if (i < NN) cursor[i] = boff[blockIdx.x] + part[t] - v;
}

// atomic-free scatter: p = cursor_base[d] + rank[e]
__global__ __launch_bounds__(256) void k_scatter(const int* __restrict__ eidx,
                                                 const int* __restrict__ cursor,
                                                 const int* __restrict__ rank_,
                                                 unsigned long long* __restrict__ sedge,
                                                 const int* __restrict__ flags) {
  const int i64 = flags[1];
  long e = (long)blockIdx.x * 256 + threadIdx.x;
  if (e < NE) {
    int s = ldidx(eidx, e, i64);
    int d = ldidx(eidx, NE + e, i64);
    int p = cursor[d] + rank_[e];
    sedge[p] = ((unsigned long long)(unsigned)d << 32) | (unsigned)s;
  }
}

// ---------------- Kernel 1: si1 = irreps_linear(nodes) via MFMA -> packed bf16 ---
__global__ __launch_bounds__(256) void k_linear1(
    const void* __restrict__ nodes,
    const unsigned short* __restrict__ w012p,
    unsigned short* __restrict__ si1,
    float* __restrict__ conv,
    const int* __restrict__ flags) {
  const int f32 = flags[0];
  __shared__ __align__(16) unsigned short wf[3072];    // 6 frags x 512 shorts
  __shared__ __align__(16) unsigned int xs32[64 * 145];// 64 rows x 290 bf16
  int tid = threadIdx.x, lane = tid & 63, wid = tid >> 6;
  for (int idx = tid; idx < 384; idx += 256)
    ((uint4*)wf)[idx] = ((const uint4*)w012p)[idx];
  long nbase = (long)blockIdx.x * 64;
  for (int idx = tid; idx < 64 * 144; idx += 256) {
    int row = idx / 144, cp = idx - row * 144;
    long rowg = nbase + row; if (rowg >= NN) rowg = NN - 1;
    unsigned v;
    if (f32) {
      const float* rp = (const float*)nodes + rowg * DIMX + 2 * cp;
      v = ((unsigned)f2b(rp[1]) << 16) | f2b(rp[0]);
    } else {
      v = ((const unsigned*)nodes)[rowg * 144 + cp];
    }
    xs32[row * 145 + cp] = v;
  }
  {
    float4 z; z.x = 0.f; z.y = 0.f; z.z = 0.f; z.w = 0.f;
    long start = nbase * DIMX / 4;
    long end = start + 64 * DIMX / 4;
    long lim = (long)NN * DIMX / 4;
    if (end > lim) end = lim;
    float4* cz = (float4*)conv;
    for (long idx = start + tid; idx < end; idx += 256) cz[idx] = z;
  }
  __syncthreads();
  long tbase = nbase + (long)wid * 16;
  if (tbase >= NN) return;
  const int q = lane >> 4, colA = lane & 15;
  const unsigned short* xs16 = (const unsigned short*)xs32;
  const int rb = (wid * 16 + colA) * 290;
  short8 a0f, a1f0, a1f1, a1f2, a2f0, a2f1, a2f2, a2f3, a2f4;
  #pragma unroll
  for (int i = 0; i < 8; ++i) {
    int k = q * 8 + i;
    a0f[i]  = (short)xs16[rb + k];
    a1f0[i] = (short)xs16[rb + 32 + 3 * k + 0];
    a1f1[i] = (short)xs16[rb + 32 + 3 * k + 1];
    a1f2[i] = (short)xs16[rb + 32 + 3 * k + 2];
    a2f0[i] = (short)xs16[rb + 128 + 5 * k + 0];
    a2f1[i] = (short)xs16[rb + 128 + 5 * k + 1];
    a2f2[i] = (short)xs16[rb + 128 + 5 * k + 2];
    a2f3[i] = (short)xs16[rb + 128 + 5 * k + 3];
    a2f4[i] = (short)xs16[rb + 128 + 5 * k + 4];
  }
  const short8* wv = (const short8*)wf;
  float4v zf = {0.f, 0.f, 0.f, 0.f};
  float4v D0[2], D1[3][2], D2[5][2];
  #pragma unroll
  for (int t = 0; t < 2; ++t) {
    D0[t]    = __builtin_amdgcn_mfma_f32_16x16x32_bf16(a0f,  wv[(0 + t) * 64 + lane], zf, 0, 0, 0);
    D1[0][t] = __builtin_amdgcn_mfma_f32_16x16x32_bf16(a1f0, wv[(2 + t) * 64 + lane], zf, 0, 0, 0);
    D1[1][t] = __builtin_amdgcn_mfma_f32_16x16x32_bf16(a1f1, wv[(2 + t) * 64 + lane], zf, 0, 0, 0);
    D1[2][t] = __builtin_amdgcn_mfma_f32_16x16x32_bf16(a1f2, wv[(2 + t) * 64 + lane], zf, 0, 0, 0);
    D2[0][t] = __builtin_amdgcn_mfma_f32_16x16x32_bf16(a2f0, wv[(4 + t) * 64 + lane], zf, 0, 0, 0);
    D2[1][t] = __builtin_amdgcn_mfma_f32_16x16x32_bf16(a2f1, wv[(4 + t) * 64 + lane], zf, 0, 0, 0);
    D2[2][t] = __builtin_amdgcn_mfma_f32_16x16x32_bf16(a2f2, wv[(4 + t) * 64 + lane], zf, 0, 0, 0);
    D2[3][t] = __builtin_amdgcn_mfma_f32_16x16x32_bf16(a2f3, wv[(4 + t) * 64 + lane], zf, 0, 0, 0);
    D2[4][t] = __builtin_amdgcn_mfma_f32_16x16x32_bf16(a2f4, wv[(4 + t) * 64 + lane], zf, 0, 0, 0);
  }
  #pragma unroll
  for (int t = 0; t < 2; ++t) {
    #pragma unroll
    for (int r = 0; r < 4; ++r) {
      long node = tbase + q * 4 + r;
      if (node < NN) {
        int mj = t * 16 + colA;
        unsigned short* row = si1 + (size_t)node * DIMX;
        short8 pk;
        pk[0] = (short)f2b(D0[t][r]);
        pk[1] = (short)f2b(D1[0][t][r]);
        pk[2] = (short)f2b(D1[1][t][r]);
        pk[3] = (short)f2b(D1[2][t][r]);
        pk[4] = (short)f2b(D2[0][t][r]);
        pk[5] = (short)f2b(D2[1][t][r]);
        pk[6] = (short)f2b(D2[2][t][r]);
        pk[7] = (short)f2b(D2[3][t][r]);
        *(short8*)(row + mj * 8) = pk;
        row[256 + mj] = f2b(D2[4][t][r]);
      }
    }
  }
}

// ---- flush helper: merge halves, then plain-store (exclusive owner) or atomic ----
__device__ __forceinline__ void flushrow(float* __restrict__ conv, unsigned dstn,
                                         float accv[9], int h, int o0, int o1, int o2,
                                         bool at) {
  float tot[9];
  #pragma unroll
  for (int r = 0; r < 9; ++r) tot[r] = accv[r] + __shfl_xor(accv[r], 32, 64);
  float* cv = conv + (size_t)dstn * DIMX;
  if (at) {
    if (h == 0) {
      atomicAdd(cv + o0, tot[0]);
      atomicAdd(cv + o1, tot[1]); atomicAdd(cv + o1 + 1, tot[2]); atomicAdd(cv + o1 + 2, tot[3]);
      atomicAdd(cv + o2, tot[4]);
    } else {
      atomicAdd(cv + o2 + 1, tot[5]); atomicAdd(cv + o2 + 2, tot[6]);
      atomicAdd(cv + o2 + 3, tot[7]); atomicAdd(cv + o2 + 4, tot[8]);
    }
  } else {
    if (h == 0) {
      cv[o0] = tot[0];
      cv[o1] = tot[1]; cv[o1 + 1] = tot[2]; cv[o1 + 2] = tot[3];
      cv[o2] = tot[4];
    } else {
      cv[o2 + 1] = tot[5]; cv[o2 + 2] = tot[6];
      cv[o2 + 3] = tot[7]; cv[o2 + 4] = tot[8];
    }
  }
  #pragma unroll
  for (int r = 0; r < 9; ++r) accv[r] = 0.f;
}

// ---------------- Kernel 3: fused edge kernel (dst-sorted edges) ----------------
// REVERTED to the R12-measured 224us version: wr2t staged in LDS, wall pitch 18,
// 4-deep prefetch ring, 128-edge wave windows, run ownership, plain stores.
__global__ __launch_bounds__(256) void k_edges(
    const void* __restrict__ pos,
    const unsigned long long* __restrict__ sedge,
    const void* __restrict__ Wr1,
    const void* __restrict__ br1,
    const unsigned short* __restrict__ wr2p,
    const unsigned short* __restrict__ si1,
    float* __restrict__ conv,
    const int* __restrict__ flags) {
  const int f32 = flags[0];
  __shared__ __align__(16) unsigned short wr2t[14336];   // 28 fragments x 512 shorts
  __shared__ __align__(16) unsigned short wall[4][4032]; // per-wave w for current 16-edge group
  __shared__ __align__(16) float wr1s[576];              // Wr1 [8][64] + br1 [64]
  __shared__ __align__(16) float geomW[4][16][8];        // per-wave Y for current group
  __shared__ __align__(16) float rbfW[4][16][8];         // per-wave rbf for current group
  __shared__ unsigned int sdvR[4][2][2][16];             // per-wave ring of 2 groups: src/dst
  int tid = threadIdx.x, lane = tid & 63, wid = tid >> 6;

  for (int idx = tid; idx < 1792; idx += 256)
    ((uint4*)wr2t)[idx] = ((const uint4*)wr2p)[idx];
  for (int idx = tid; idx < 512; idx += 256) wr1s[idx] = ldf(Wr1, idx, f32);
  if (tid < 64) wr1s[512 + tid] = ldf(br1, tid, f32);
  __syncthreads();

  size_t we = (size_t)blockIdx.x * 512 + (size_t)wid * 128;
  if (we >= (size_t)NE) return;

  const int q = lane >> 4, colA = lane & 15;
  const int h = lane >> 5, m = lane & 31;
  const int o0 = m, o1 = 32 + 3 * m, o2 = 128 + 5 * m;
  unsigned short* WL = wall[wid];

  unsigned left_dst = 0xffffffffu, right_dst = 0xffffffffu;
  if (we > 0) left_dst = (unsigned)(sedge[we - 1] >> 32);
  if (we + 128 < (size_t)NE) right_dst = (unsigned)(sedge[we + 128] >> 32);

  if (lane < 16) {
    unsigned long long pr = sedge[we + lane];
    sdvR[wid][0][0][lane] = (unsigned)(pr & 0xffffffffu);
    sdvR[wid][0][1][lane] = (unsigned)(pr >> 32);
  }
  asm volatile("" ::: "memory");

  unsigned cur_d = sdvR[wid][0][1][0];
  bool first = true;
  float accv[9];
  #pragma unroll
  for (int r = 0; r < 9; ++r) accv[r] = 0.f;

  uint4 A0, A1, A2, A3; unsigned short E0, E1, E2, E3;
  {
    const char* rp;
    unsigned s;
    s = sdvR[wid][0][0][0 + h]; rp = (const char*)si1 + (size_t)s * 576;
    A0 = *(const uint4*)(rp + m * 16); E0 = *(const unsigned short*)(rp + 512 + 2 * m);
    s = sdvR[wid][0][0][2 + h]; rp = (const char*)si1 + (size_t)s * 576;
    A1 = *(const uint4*)(rp + m * 16); E1 = *(const unsigned short*)(rp + 512 + 2 * m);
    s = sdvR[wid][0][0][4 + h]; rp = (const char*)si1 + (size_t)s * 576;
    A2 = *(const uint4*)(rp + m * 16); E2 = *(const unsigned short*)(rp + 512 + 2 * m);
    s = sdvR[wid][0][0][6 + h]; rp = (const char*)si1 + (size_t)s * 576;
    A3 = *(const uint4*)(rp + m * 16); E3 = *(const unsigned short*)(rp + 512 + 2 * m);
  }

  #pragma unroll 1
  for (int g = 0; g < 8; ++g) {
    if (lane < 16) {
      if (g < 7) {
        unsigned long long pr = sedge[we + (size_t)(g + 1) * 16 + lane];
        sdvR[wid][(g + 1) & 1][0][lane] = (unsigned)(pr & 0xffffffffu);
        sdvR[wid][(g + 1) & 1][1][lane] = (unsigned)(pr >> 32);
      }
      unsigned s = sdvR[wid][g & 1][0][lane];
      unsigned d = sdvR[wid][g & 1][1][lane];
      float rx = ldf(pos, 3 * (long)s, f32)     - ldf(pos, 3 * (long)d, f32);
      float ry = ldf(pos, 3 * (long)s + 1, f32) - ldf(pos, 3 * (long)d + 1, f32);
      float rz = ldf(pos, 3 * (long)s + 2, f32) - ldf(pos, 3 * (long)d + 2, f32);
      float dd = sqrtf(rx * rx + ry * ry + rz * rz + 1e-12f);
      float inv = 1.0f / dd;
      float ux = rx * inv, uy = ry * inv, uz = rz * inv;
      geomW[wid][lane][0] = ux; geomW[wid][lane][1] = uy; geomW[wid][lane][2] = uz;
      geomW[wid][lane][3] = ux * uy;
      geomW[wid][lane][4] = uy * uz;
      geomW[wid][lane][5] = (3.f * uz * uz - 1.f) * 0.28867513459481287f;
      geomW[wid][lane][6] = ux * uz;
      geomW[wid][lane][7] = (ux * ux - uy * uy) * 0.5f;
      #pragma unroll
      for (int k = 0; k < 8; ++k) {
        float t = dd - (float)k * (5.0f / 7.0f);
        rbfW[wid][lane][k] = __expf(-t * t);
      }
    }
    asm volatile("" ::: "memory");

    short8 afrag0, afrag1;
    {
      const float* rb = &rbfW[wid][colA][0];
      float rbv[8];
      #pragma unroll
      for (int r = 0; r < 8; ++r) rbv[r] = rb[r];
      float a0[8], a1[8];
      {
        float4v b0 = *(const float4v*)&wr1s[512 + q * 8];
        float4v b1 = *(const float4v*)&wr1s[512 + q * 8 + 4];
        float4v b2 = *(const float4v*)&wr1s[512 + 32 + q * 8];
        float4v b3 = *(const float4v*)&wr1s[512 + 32 + q * 8 + 4];
        #pragma unroll
        for (int i = 0; i < 4; ++i) {
          a0[i] = b0[i]; a0[4 + i] = b1[i];
          a1[i] = b2[i]; a1[4 + i] = b3[i];
        }
      }
      #pragma unroll
      for (int r = 0; r < 8; ++r) {
        float4v wA = *(const float4v*)&wr1s[r * 64 + q * 8];
        float4v wB = *(const float4v*)&wr1s[r * 64 + q * 8 + 4];
        float4v wC = *(const float4v*)&wr1s[r * 64 + 32 + q * 8];
        float4v wD = *(const float4v*)&wr1s[r * 64 + 32 + q * 8 + 4];
        float rv = rbv[r];
        #pragma unroll
        for (int i = 0; i < 4; ++i) {
          a0[i]     += rv * wA[i];
          a0[4 + i] += rv * wB[i];
          a1[i]     += rv * wC[i];
          a1[4 + i] += rv * wD[i];
        }
      }
      #pragma unroll
      for (int i = 0; i < 8; ++i) {
        float a = a0[i];
        afrag0[i] = (short)f2b(0.25f * a / (1.f + __expf(-a)));
        float a2 = a1[i];
        afrag1[i] = (short)f2b(0.25f * a2 / (1.f + __expf(-a2)));
      }
    }

    {
      float4v acc[14];
      #pragma unroll
      for (int t = 0; t < 14; ++t) {
        short8 b0 = *(const short8*)&wr2t[(t * 2 + 0) * 512 + lane * 8];
        short8 b1 = *(const short8*)&wr2t[(t * 2 + 1) * 512 + lane * 8];
        float4v c = {0.f, 0.f, 0.f, 0.f};
        c = __builtin_amdgcn_mfma_f32_16x16x32_bf16(afrag0, b0, c, 0, 0, 0);
        c = __builtin_amdgcn_mfma_f32_16x16x32_bf16(afrag1, b1, c, 0, 0, 0);
        acc[t] = c;
      }
      #pragma unroll
      for (int t = 0; t < 14; ++t) {
        int j = t * 16 + colA;
        #pragma unroll
        for (int r = 0; r < 4; ++r)
          WL[j * 18 + q * 4 + r] = f2b(acc[t][r]);
      }
    }
    asm volatile("" ::: "memory");

    #pragma unroll
    for (int ii = 0; ii < 8; ++ii) {
      uint4 cur; unsigned short ce;
      switch (ii & 3) {
        case 0: cur = A0; ce = E0; break;
        case 1: cur = A1; ce = E1; break;
        case 2: cur = A2; ce = E2; break;
        default: cur = A3; ce = E3; break;
      }
      if (!(g == 7 && ii >= 4)) {
        int adv = 2 * ii + 8 + h;
        int pslot = (g + (adv >> 4)) & 1;
        int pidx = adv & 15;
        unsigned ps = sdvR[wid][pslot][0][pidx];
        const char* rp = (const char*)si1 + (size_t)ps * 576;
        uint4 pa = *(const uint4*)(rp + m * 16);
        unsigned short pe = *(const unsigned short*)(rp + 512 + 2 * m);
        switch (ii & 3) {
          case 0: A0 = pa; E0 = pe; break;
          case 1: A1 = pa; E1 = pe; break;
          case 2: A2 = pa; E2 = pe; break;
          default: A3 = pa; E3 = pe; break;
        }
      }

      unsigned dn0 = sdvR[wid][g & 1][1][2 * ii];
      unsigned dn1 = sdvR[wid][g & 1][1][2 * ii + 1];

      if (dn0 != cur_d) {
        bool at = first && (cur_d == left_dst);
        flushrow(conv, cur_d, accv, h, o0, o1, o2, at);
        first = false;
        cur_d = dn0;
      }

      float x0v = b2f_lo(cur.x), x1a = b2f_hi(cur.x);
      float x1b = b2f_lo(cur.y), x1c = b2f_hi(cur.y);
      float x2a = b2f_lo(cur.z), x2b = b2f_hi(cur.z);
      float x2c = b2f_lo(cur.w), x2d = b2f_hi(cur.w);
      float x2e = b2f(ce);
      const int elc = 2 * ii + h;
      float w0 = b2f(WL[(0 * 32 + m) * 18 + elc]);
      float w1 = b2f(WL[(1 * 32 + m) * 18 + elc]);
      float w2 = b2f(WL[(2 * 32 + m) * 18 + elc]);
      float w3 = b2f(WL[(3 * 32 + m) * 18 + elc]);
      float w4 = b2f(WL[(4 * 32 + m) * 18 + elc]);
      float w5 = b2f(WL[(5 * 32 + m) * 18 + elc]);
      float w6 = b2f(WL[(6 * 32 + m) * 18 + elc]);
      float4v gv0 = *(const float4v*)&geomW[wid][elc][0];
      float4v gv1 = *(const float4v*)&geomW[wid][elc][4];
      float y1x = gv0[0], y1y = gv0[1], y1z = gv0[2], y20 = gv0[3];
      float y21 = gv1[0], y22 = gv1[1], y23 = gv1[2], y24 = gv1[3];
      float d1 = x1a * y1x + x1b * y1y + x1c * y1z;
      float d2 = x2a * y20 + x2b * y21 + x2c * y22 + x2d * y23 + x2e * y24;
      float w3x0 = w3 * x0v, w5x0 = w5 * x0v;
      float v[9];
      v[0] = w0 * x0v + w4 * d1 + w6 * d2;
      v[1] = w1 * x1a + w3x0 * y1x;
      v[2] = w1 * x1b + w3x0 * y1y;
      v[3] = w1 * x1c + w3x0 * y1z;
      v[4] = w2 * x2a + w5x0 * y20;
      v[5] = w2 * x2b + w5x0 * y21;
      v[6] = w2 * x2c + w5x0 * y22;
      v[7] = w2 * x2d + w5x0 * y23;
      v[8] = w2 * x2e + w5x0 * y24;

      if (dn1 == dn0) {
        #pragma unroll
        for (int r = 0; r < 9; ++r) accv[r] += v[r];
      } else {
        if (h == 0) {
          #pragma unroll
          for (int r = 0; r < 9; ++r) accv[r] += v[r];
        }
        bool at = first && (cur_d == left_dst);
        flushrow(conv, cur_d, accv, h, o0, o1, o2, at);
        first = false;
        cur_d = dn1;
        if (h == 1) {
          #pragma unroll
          for (int r = 0; r < 9; ++r) accv[r] += v[r];
        }
      }
    }
  }
  {
    bool at = (cur_d == right_dst) || (first && (cur_d == left_dst));
    flushrow(conv, cur_d, accv, h, o0, o1, o2, at);
  }
}

// ---------------- Kernel 4: si2 = linear(conv) via MFMA; mixed; gate -> fp32 ----
__global__ __launch_bounds__(256) void k_gate(
    const float* __restrict__ conv,
    const void* __restrict__ nodes,
    const unsigned short* __restrict__ w012p,
    const unsigned short* __restrict__ wgp,
    float* __restrict__ out,
    const int* __restrict__ flags) {
  const int f32 = flags[0];
  __shared__ __align__(16) unsigned short wf[5120];     // 3072 w012 + 2048 wg
  __shared__ __align__(16) unsigned int xs32[64 * 145]; // 64 rows x 290 bf16
  __shared__ unsigned short m0b[4][16][40];             // mixed x0 (bf16)
  __shared__ float gsb[4][16][66];                      // gate values
  int tid = threadIdx.x, lane = tid & 63, wid = tid >> 6;
  for (int idx = tid; idx < 384; idx += 256)
    ((uint4*)wf)[idx] = ((const uint4*)w012p)[idx];
  for (int idx = tid; idx < 256; idx += 256)
    ((uint4*)(wf + 3072))[idx] = ((const uint4*)wgp)[idx];
  long nbase = (long)blockIdx.x * 64;
  for (int idx = tid; idx < 64 * 144; idx += 256) {
    int row = idx / 144, cp = idx - row * 144;
    long rowg = nbase + row; if (rowg >= NN) rowg = NN - 1;
    const float* rp = conv + rowg * DIMX + 2 * cp;
    xs32[row * 145 + cp] = ((unsigned)f2b(rp[1]) << 16) | f2b(rp[0]);
  }
  __syncthreads();
  long tbase = nbase + (long)wid * 16;
  if (tbase >= NN) return;
  const int q = lane >> 4, colA = lane & 15;
  const unsigned short* xs16 = (const unsigned short*)xs32;
  const int rb = (wid * 16 + colA) * 290;
  short8 a0f, a1f0, a1f1, a1f2, a2f0, a2f1, a2f2, a2f3, a2f4;
  #pragma unroll
  for (int i = 0; i < 8; ++i) {
    int k = q * 8 + i;
    a0f[i]  = (short)xs16[rb + k];
    a1f0[i] = (short)xs16[rb + 32 + 3 * k + 0];
    a1f1[i] = (short)xs16[rb + 32 + 3 * k + 1];
    a1f2[i] = (short)xs16[rb + 32 + 3 * k + 2];
    a2f0[i] = (short)xs16[rb + 128 + 5 * k + 0];
    a2f1[i] = (short)xs16[rb + 128 + 5 * k + 1];
    a2f2[i] = (short)xs16[rb + 128 + 5 * k + 2];
    a2f3[i] = (short)xs16[rb + 128 + 5 * k + 3];
    a2f4[i] = (short)xs16[rb + 128 + 5 * k + 4];
  }
  const short8* wv = (const short8*)wf;
  const short8* wg = (const short8*)(wf + 3072);
  float4v zf = {0.f, 0.f, 0.f, 0.f};
  float mixed0[2][4];
  #pragma unroll
  for (int t = 0; t < 2; ++t) {
    float4v d = __builtin_amdgcn_mfma_f32_16x16x32_bf16(a0f, wv[(0 + t) * 64 + lane], zf, 0, 0, 0);
    #pragma unroll
    for (int r = 0; r < 4; ++r) {
      long node = tbase + q * 4 + r;
      long nc = node < NN ? node : NN - 1;
      float v = d[r] + ldf(nodes, nc * DIMX + t * 16 + colA, f32);
      mixed0[t][r] = v;
      m0b[wid][q * 4 + r][t * 16 + colA] = f2b(v);
    }
  }
  asm volatile("" ::: "memory");
  short8 amf;
  #pragma unroll
  for (int i = 0; i < 8; ++i) amf[i] = (short)m0b[wid][colA][q * 8 + i];
  #pragma unroll
  for (int t = 0; t < 4; ++t) {
    float4v d = __builtin_amdgcn_mfma_f32_16x16x32_bf16(amf, wg[t * 64 + lane], zf, 0, 0, 0);
    #pragma unroll
    for (int r = 0; r < 4; ++r)
      gsb[wid][q * 4 + r][t * 16 + colA] = 1.f / (1.f + __expf(-d[r]));
  }
  asm volatile("" ::: "memory");
  float4v D1[3][2], D2[5][2];
  #pragma unroll
  for (int t = 0; t < 2; ++t) {
    D1[0][t] = __builtin_amdgcn_mfma_f32_16x16x32_bf16(a1f0, wv[(2 + t) * 64 + lane], zf, 0, 0, 0);
    D1[1][t] = __builtin_amdgcn_mfma_f32_16x16x32_bf16(a1f1, wv[(2 + t) * 64 + lane], zf, 0, 0, 0);
    D1[2][t] = __builtin_amdgcn_mfma_f32_16x16x32_bf16(a1f2, wv[(2 + t) * 64 + lane], zf, 0, 0, 0);
    D2[0][t] = __builtin_amdgcn_mfma_f32_16x16x32_bf16(a2f0, wv[(4 + t) * 64 + lane], zf, 0, 0, 0);
    D2[1][t] = __builtin_amdgcn_mfma_f32_16x16x32_bf16(a2f1, wv[(4 + t) * 64 + lane], zf, 0, 0, 0);
    D2[2][t] = __builtin_amdgcn_mfma_f32_16x16x32_bf16(a2f2, wv[(4 + t) * 64 + lane], zf, 0, 0, 0);
    D2[3][t] = __builtin_amdgcn_mfma_f32_16x16x32_bf16(a2f3, wv[(4 + t) * 64 + lane], zf, 0, 0, 0);
    D2[4][t] = __builtin_amdgcn_mfma_f32_16x16x32_bf16(a2f4, wv[(4 + t) * 64 + lane], zf, 0, 0, 0);
  }
  #pragma unroll
  for (int t = 0; t < 2; ++t) {
    #pragma unroll
    for (int r = 0; r < 4; ++r) {
      long node = tbase + q * 4 + r;
      if (node < NN) {
        int nl = q * 4 + r;
        int mj = t * 16 + colA;
        float* orow = out + (size_t)node * DIMX;
        const long nrow = node * DIMX;
        float v0 = mixed0[t][r];
        orow[mj] = v0 / (1.f + __expf(-v0));
        float g1 = gsb[wid][nl][mj];
        float g2 = gsb[wid][nl][32 + mj];
        #pragma unroll
        for (int c = 0; c < 3; ++c) {
          float v = D1[c][t][r] + ldf(nodes, nrow + 32 + 3 * mj + c, f32);
          orow[32 + 3 * mj + c] = v * g1;
        }
        #pragma unroll
        for (int c = 0; c < 5; ++c) {
          float v = D2[c][t][r] + ldf(nodes, nrow + 128 + 5 * mj + c, f32);
          orow[128 + 5 * mj + c] = v * g2;
        }
      }
    }
  }
}

extern "C" void kernel_launch(void* const* d_in, const int* in_sizes, int n_in,
                              void* d_out, int out_size, void* d_ws, size_t ws_size,
                              hipStream_t stream) {
  const void* nodes = d_in[0];
  const void* pos   = d_in[1];
  const void* W0    = d_in[2];
  const void* W1    = d_in[3];
  const void* W2    = d_in[4];
  const void* Wr1   = d_in[5];
  const void* br1   = d_in[6];
  const void* Wr2   = d_in[7];
  const void* Wg    = d_in[8];
  const int* eidx   = (const int*)d_in[10];

  // workspace layout
  int* flags = (int*)d_ws;
  unsigned short* si1 = (unsigned short*)((char*)d_ws + 256);
  size_t conv_off = 256 + (size_t)NN * DIMX * 2;                 // 28,800,256
  float* conv = (float*)((char*)d_ws + conv_off);
  size_t cnt_off = conv_off + (size_t)NN * DIMX * 4;             // 86,400,256
  int* cnt    = (int*)((char*)d_ws + cnt_off);
  int* cursor = (int*)((char*)d_ws + cnt_off + (size_t)NN * 4);  // 86,600,256
  unsigned long long* sedge =
      (unsigned long long*)((char*)d_ws + cnt_off + 2 * (size_t)NN * 4);  // 86,800,256
  unsigned short* wr2p =
      (unsigned short*)((char*)d_ws + cnt_off + 2 * (size_t)NN * 4 + (size_t)NE * 8); // 93,200,256
  unsigned short* w012p = wr2p + 28 * 512;                        // +28,672 B
  unsigned short* wgp   = w012p + 6 * 512;                        // +6,144 B
  int* bsum = (int*)(wgp + 4 * 512);                              // +4,096 B
  int* boff = bsum + 256;
  int* rank_ = boff + 256;                                        // NE ints (3.2 MB)
  float* out = (float*)d_out;

  hipLaunchKernelGGL(k_prep, dim3((NN + 255) / 256), dim3(256), 0, stream,
                     W0, W1, W2, Wg, Wr2,
                     (const unsigned short*)pos, eidx,
                     wr2p, w012p, wgp, cnt, flags);
  // counting sort of edges by dst (hist+rank, 3-stage scan, atomic-free scatter)
  hipLaunchKernelGGL(k_hist, dim3((NE + 255) / 256), dim3(256), 0, stream,
                     eidx, cnt, rank_, flags);
  hipLaunchKernelGGL(k_scan1, dim3((NN + 255) / 256), dim3(256), 0, stream, cnt, bsum);
  hipLaunchKernelGGL(k_scan2, dim3(1), dim3(256), 0, stream, bsum, boff);
  hipLaunchKernelGGL(k_scan3, dim3((NN + 255) / 256), dim3(256), 0, stream, cnt, boff, cursor);
  hipLaunchKernelGGL(k_scatter, dim3((NE + 255) / 256), dim3(256), 0, stream,
                     eidx, cursor, rank_, sedge, flags);
  // node pipeline (MFMA + coalesced LDS staging; k_linear1 also zeroes conv)
  hipLaunchKernelGGL(k_linear1, dim3((NN + 63) / 64), dim3(256), 0, stream,
                     nodes, w012p, si1, conv, flags);
  hipLaunchKernelGGL(k_edges, dim3((NE + 511) / 512), dim3(256), 0, stream,
                     pos, sedge, Wr1, br1, wr2p, si1, conv, flags);
  hipLaunchKernelGGL(k_gate, dim3((NN + 63) / 64), dim3(256), 0, stream,
                     conv, nodes, w012p, wgp, out, flags);
}